// Round 9
// baseline (308.324 us; speedup 1.0000x reference)
//
#include <hip/hip_runtime.h>
#include <hip/hip_bf16.h>
#include <math.h>

#define N_EMBD 768
#define N_HEAD 12
#define BATCH  2
#define SEQ    2048
#define ROWS   (BATCH*SEQ)   // 4096
#define C3     (3*N_EMBD)    // 2304

typedef __bf16 bf16;
typedef __attribute__((ext_vector_type(8))) __bf16 bf16x8;
typedef __attribute__((ext_vector_type(4))) float f32x4;

// async global->LDS, 16B per lane. LDS dest must be wave-uniform base + 16*lane.
__device__ __forceinline__ void async16(const bf16* g, bf16* l) {
    __builtin_amdgcn_global_load_lds(
        (const __attribute__((address_space(1))) uint32_t*)g,
        (__attribute__((address_space(3))) uint32_t*)l, 16, 0, 0);
}

// ---------------- merged transpose+cast for all 4 weights: in[K,N] -> out[N,K] ----------------
__global__ __launch_bounds__(256) void k_transpose_all(
    const float* __restrict__ w0, bf16* __restrict__ o0,   // attn K=768  N=2304 (1728 tiles)
    const float* __restrict__ w1, bf16* __restrict__ o1,   // proj K=768  N=768  (576)
    const float* __restrict__ w2, bf16* __restrict__ o2,   // fc   K=768  N=3072 (2304)
    const float* __restrict__ w3, bf16* __restrict__ o3)   // mlp  K=3072 N=768  (2304)
{
    __shared__ bf16 tile[32][33];
    int bid = blockIdx.x;
    const float* in; bf16* out; int K, N, local;
    if      (bid < 1728) { in = w0; out = o0; K = 768;  N = 2304; local = bid; }
    else if (bid < 2304) { in = w1; out = o1; K = 768;  N = 768;  local = bid - 1728; }
    else if (bid < 4608) { in = w2; out = o2; K = 768;  N = 3072; local = bid - 2304; }
    else                 { in = w3; out = o3; K = 3072; N = 768;  local = bid - 4608; }
    int nt = N / 32;
    int n0 = (local % nt) * 32, k0 = (local / nt) * 32;
    int tc = threadIdx.x & 31, tr = threadIdx.x >> 5;
    #pragma unroll
    for (int i = 0; i < 4; i++) {
        int r = tr + i * 8;
        tile[r][tc] = (bf16)in[(size_t)(k0 + r) * N + n0 + tc];
    }
    __syncthreads();
    #pragma unroll
    for (int i = 0; i < 4; i++) {
        int r = tr + i * 8;
        out[(size_t)(n0 + r) * K + k0 + tc] = tile[tc][r];
    }
}

// ---------------- V transpose: qkv[t][2C + h*64 + d] -> vt[(bh*64+d)*SEQ + t] ----------------
__global__ __launch_bounds__(256) void k_vtrans(
    const bf16* __restrict__ qkv, bf16* __restrict__ vt)
{
    __shared__ bf16 tile[32][33];
    int tt = blockIdx.x;                 // t tile (SEQ/32)
    int bh = blockIdx.y;                 // 24
    int dt = blockIdx.z;                 // d tile (2)
    int b = bh / N_HEAD, h = bh % N_HEAD;
    int tc = threadIdx.x & 31, tr = threadIdx.x >> 5;
    #pragma unroll
    for (int i = 0; i < 4; i++) {
        int r = tr + i * 8;              // t offset
        tile[r][tc] = qkv[(size_t)(b * SEQ + tt * 32 + r) * C3 + 2 * N_EMBD + h * 64 + dt * 32 + tc];
    }
    __syncthreads();
    #pragma unroll
    for (int i = 0; i < 4; i++) {
        int r = tr + i * 8;              // d offset
        vt[(size_t)(bh * 64 + dt * 32 + r) * SEQ + tt * 32 + tc] = tile[tc][r];
    }
}

// ---------------- LayerNorm fp32 -> bf16, one wave per row, float4 loads ----------------
__global__ __launch_bounds__(256) void k_layernorm(
    const float* __restrict__ x, const float* __restrict__ g,
    const float* __restrict__ b, bf16* __restrict__ out)
{
    int wave = threadIdx.x >> 6, lane = threadIdx.x & 63;
    int row = blockIdx.x * 4 + wave;
    const float4* xr = (const float4*)(x + (size_t)row * N_EMBD);
    const float4* g4 = (const float4*)g;
    const float4* b4 = (const float4*)b;
    float4 v[3];
    float s = 0.f, sq = 0.f;
    #pragma unroll
    for (int i = 0; i < 3; i++) {
        v[i] = xr[lane + 64 * i];
        s  += v[i].x + v[i].y + v[i].z + v[i].w;
        sq += v[i].x * v[i].x + v[i].y * v[i].y + v[i].z * v[i].z + v[i].w * v[i].w;
    }
    #pragma unroll
    for (int off = 32; off > 0; off >>= 1) {
        s  += __shfl_xor(s, off);
        sq += __shfl_xor(sq, off);
    }
    float mu  = s * (1.f / N_EMBD);
    float var = sq * (1.f / N_EMBD) - mu * mu;
    float rs  = rsqrtf(var + 1e-5f);
    bf16* orow = out + (size_t)row * N_EMBD;
    #pragma unroll
    for (int i = 0; i < 3; i++) {
        float4 gv = g4[lane + 64 * i], bv = b4[lane + 64 * i];
        union { ushort4 u4; bf16 e[4]; } pk;
        pk.e[0] = (bf16)((v[i].x - mu) * rs * gv.x + bv.x);
        pk.e[1] = (bf16)((v[i].y - mu) * rs * gv.y + bv.y);
        pk.e[2] = (bf16)((v[i].z - mu) * rs * gv.z + bv.z);
        pk.e[3] = (bf16)((v[i].w - mu) * rs * gv.w + bv.w);
        *(ushort4*)&orow[(lane + 64 * i) * 4] = pk.u4;
    }
}

// ---------------- GEMM: out = act(A[M,K] @ Bt[N,K]^T + bias) (+res) ----------------
// 128xBN tile, BK=32 (m97 config: 4 async16/thread, 2x finer pipeline than BK=64),
// XOR swizzle for 64B rows: slot sc holds global chunk sc^((sr^(sr>>2))&3) ->
// every 16B granule slot is exactly 2-way in b128 reads (free, m136).
template<int BN, int ACT, bool RES, bool OUT_BF16>
__global__ __launch_bounds__(256) void k_gemm(
    const bf16* __restrict__ A, const bf16* __restrict__ Bt,
    const float* __restrict__ bias, const float* __restrict__ res,
    void* __restrict__ outp, int M, int N, int K)
{
    constexpr int WC  = BN / 64;
    constexpr int WR  = 4 / WC;
    constexpr int RPW = 128 / WR;
    constexpr int MI  = RPW / 16;
    __shared__ __align__(16) bf16 As[128 * 32];
    __shared__ __align__(16) bf16 Bs[BN * 32];
    int n0 = blockIdx.x * BN, m0 = blockIdx.y * 128;
    int t = threadIdx.x;
    int lane = t & 63, wave = t >> 6;
    int wr = wave / WC, wc = wave % WC;
    int quad = lane >> 4, l16 = lane & 15;

    f32x4 acc[MI][4];
    #pragma unroll
    for (int i = 0; i < MI; i++)
        #pragma unroll
        for (int j = 0; j < 4; j++) acc[i][j] = (f32x4){0.f, 0.f, 0.f, 0.f};

    int sr = t >> 2;                         // 0..63 (row)
    int sc = t & 3;                          // chunk 0..3 (8 bf16 = 16B)
    int gsw = ((sc ^ ((sr ^ (sr >> 2)) & 3))) * 8;   // swizzled global column offset
    int rsw = (quad ^ ((l16 ^ (l16 >> 2)) & 3)) * 8; // swizzled read slot (row-dependent part
                                                     // is l16-only: tile row = 16*i + l16)

    for (int k0 = 0; k0 < K; k0 += 32) {
        __syncthreads();
        #pragma unroll
        for (int p = 0; p < 2; p++) {
            int r = sr + p * 64;
            async16(&A[(size_t)(m0 + r) * K + k0 + gsw], &As[r * 32 + sc * 8]);
        }
        #pragma unroll
        for (int p = 0; p < BN / 64; p++) {
            int r = sr + p * 64;
            async16(&Bt[(size_t)(n0 + r) * K + k0 + gsw], &Bs[r * 32 + sc * 8]);
        }
        __syncthreads();
        bf16x8 af[MI], bfv[4];
        #pragma unroll
        for (int i = 0; i < MI; i++)
            af[i]  = *(bf16x8*)&As[(wr * RPW + i * 16 + l16) * 32 + rsw];
        #pragma unroll
        for (int j = 0; j < 4; j++)
            bfv[j] = *(bf16x8*)&Bs[(wc * 64 + j * 16 + l16) * 32 + rsw];
        #pragma unroll
        for (int i = 0; i < MI; i++)
            #pragma unroll
            for (int j = 0; j < 4; j++)
                acc[i][j] = __builtin_amdgcn_mfma_f32_16x16x32_bf16(af[i], bfv[j], acc[i][j], 0, 0, 0);
    }

    float* outf = (float*)outp;
    bf16*  outb = (bf16*)outp;
    #pragma unroll
    for (int i = 0; i < MI; i++) {
        #pragma unroll
        for (int j = 0; j < 4; j++) {
            int col = n0 + wc * 64 + j * 16 + l16;
            float bv = bias[col];
            #pragma unroll
            for (int r = 0; r < 4; r++) {
                int row = m0 + wr * RPW + i * 16 + quad * 4 + r;
                float v = acc[i][j][r] + bv;
                if (ACT == 1) {
                    float z = 0.7978845608f * (v + 0.044715f * v * v * v);
                    v = v / (1.f + __expf(-2.f * z));   // 0.5v(1+tanh z) == v*sigmoid(2z)
                }
                if (RES) v += res[(size_t)row * N + col];
                if (OUT_BF16) outb[(size_t)row * N + col] = (bf16)v;
                else          outf[(size_t)row * N + col] = v;
            }
        }
    }
}

// ---------------- Flash attention v6 (r6-best): balanced constant-sum triples + dbuf ----------------
#define PS_S 72
__global__ __launch_bounds__(256) void k_flash(
    const bf16* __restrict__ qkv, const bf16* __restrict__ vt, bf16* __restrict__ y)
{
    __shared__ __align__(16) bf16 Ks[2][64 * 64];      // [buf][key][d^swz]
    __shared__ __align__(16) bf16 VTl[2][64 * 64];     // [buf][d][key^swz]
    __shared__ __align__(16) bf16 Ps[4][16 * PS_S];    // per-wave [q][key]
    int bid = blockIdx.x;
    int hi = bid >> 8;                   // 0..2
    int lo = bid & 255;
    int g  = lo >> 3;                    // 0..31
    int e  = lo & 7;                     // 0..7
    int bh = hi * 8 + e;                 // 0..23
    int qt;
    if      (hi == 0) qt = g;
    else if (hi == 1) qt = (g + 16) & 31;
    else              qt = (g < 16) ? (30 - 2 * g) : (63 - 2 * g);
    int b = bh / N_HEAD, h = bh % N_HEAD;
    int t = threadIdx.x, lane = t & 63, wave = t >> 6;
    int quad = lane >> 4, l16 = lane & 15;
    int qbase = qt * 64 + wave * 16;

    // Q fragments, pre-scaled by 1/8
    bf16x8 qa[2];
    {
        const bf16* qrow = qkv + (size_t)(b * SEQ + qbase + l16) * C3 + h * 64;
        #pragma unroll
        for (int kh = 0; kh < 2; kh++) {
            union { uint4 u4; bf16 e8[8]; bf16x8 vv; } uq;
            uq.u4 = *(const uint4*)&qrow[quad * 8 + kh * 32];
            #pragma unroll
            for (int j = 0; j < 8; j++) uq.e8[j] = (bf16)((float)uq.e8[j] * 0.125f);
            qa[kh] = uq.vv;
        }
    }
    float l_part[4] = {0.f, 0.f, 0.f, 0.f};
    f32x4 o[4];
    #pragma unroll
    for (int j = 0; j < 4; j++) o[j] = (f32x4){0.f, 0.f, 0.f, 0.f};

    int sr = t >> 3;                 // 0..31
    int sc = t & 7;                  // 16B chunk
    int gsw = (sc ^ (sr & 7)) * 8;   // swizzled column offset

    const bf16* kg = qkv + (size_t)b * SEQ * C3 + N_EMBD + h * 64;
    const bf16* vg = vt + (size_t)bh * 64 * SEQ;

    auto stage = [&](int tile, int bufi) {
        int k0 = tile * 64;
        #pragma unroll
        for (int p = 0; p < 2; p++) {
            int rr = sr + 32 * p;
            async16(&kg[(size_t)(k0 + rr) * C3 + gsw],  &Ks[bufi][rr * 64 + sc * 8]);
            async16(&vg[(size_t)rr * SEQ + k0 + gsw], &VTl[bufi][rr * 64 + sc * 8]);
        }
    };

    int ntiles = qt + 1;
    stage(0, 0);

    for (int tt = 0; tt < ntiles; tt++) {
        int bufi = tt & 1;
        int k0 = tt * 64;
        __syncthreads();                       // drains buf's loads (issued a full tile ago)
        if (tt + 1 < ntiles) stage(tt + 1, bufi ^ 1);

        // S = Q K^T : 4 key-tiles of 16
        f32x4 s[4];
        #pragma unroll
        for (int nt = 0; nt < 4; nt++) {
            bf16x8 b0 = *(bf16x8*)&Ks[bufi][(nt * 16 + l16) * 64 + (((quad    ) ^ (l16 & 7)) * 8)];
            bf16x8 b1 = *(bf16x8*)&Ks[bufi][(nt * 16 + l16) * 64 + (((quad + 4) ^ (l16 & 7)) * 8)];
            f32x4 z = (f32x4){0.f, 0.f, 0.f, 0.f};
            z = __builtin_amdgcn_mfma_f32_16x16x32_bf16(qa[0], b0, z, 0, 0, 0);
            z = __builtin_amdgcn_mfma_f32_16x16x32_bf16(qa[1], b1, z, 0, 0, 0);
            s[nt] = z;
        }
        // p = exp(s); causal zeroing only on the diagonal tile
        bool diag = (tt == qt);
        float p[4][4];
        #pragma unroll
        for (int nt = 0; nt < 4; nt++) {
            int key = k0 + nt * 16 + l16;
            #pragma unroll
            for (int r = 0; r < 4; r++) {
                float pv = __expf(s[nt][r]);
                if (diag && key > qbase + quad * 4 + r) pv = 0.f;
                p[nt][r] = pv;
                l_part[r] += pv;
            }
        }
        // P: C-layout -> per-wave LDS -> A-layout (wave-local, no block barrier)
        #pragma unroll
        for (int nt = 0; nt < 4; nt++)
            #pragma unroll
            for (int r = 0; r < 4; r++)
                Ps[wave][(quad * 4 + r) * PS_S + nt * 16 + l16] = (bf16)p[nt][r];
        bf16x8 pa[2];
        #pragma unroll
        for (int kt = 0; kt < 2; kt++)
            pa[kt] = *(bf16x8*)&Ps[wave][l16 * PS_S + kt * 32 + quad * 8];
        // O += P V
        #pragma unroll
        for (int jt = 0; jt < 4; jt++) {
            int d = jt * 16 + l16;
            #pragma unroll
            for (int kt = 0; kt < 2; kt++) {
                bf16x8 vb = *(bf16x8*)&VTl[bufi][d * 64 + (((quad + 4 * kt) ^ (l16 & 7)) * 8)];
                o[jt] = __builtin_amdgcn_mfma_f32_16x16x32_bf16(pa[kt], vb, o[jt], 0, 0, 0);
            }
        }
    }
    // epilogue: reduce row sums across the 16-lane key groups, divide, store
    #pragma unroll
    for (int r = 0; r < 4; r++) {
        #pragma unroll
        for (int off = 8; off > 0; off >>= 1) l_part[r] += __shfl_xor(l_part[r], off);
    }
    #pragma unroll
    for (int jt = 0; jt < 4; jt++)
        #pragma unroll
        for (int r = 0; r < 4; r++) {
            int q = qbase + quad * 4 + r;
            y[(size_t)(b * SEQ + q) * N_EMBD + h * 64 + jt * 16 + l16] =
                (bf16)(o[jt][r] / l_part[r]);
        }
}

// ---------------- launcher ----------------
extern "C" void kernel_launch(void* const* d_in, const int* in_sizes, int n_in,
                              void* d_out, int out_size, void* d_ws, size_t ws_size,
                              hipStream_t stream) {
    const float* x           = (const float*)d_in[0];
    const float* ln1_g       = (const float*)d_in[1];
    const float* ln1_b       = (const float*)d_in[2];
    const float* w_attn      = (const float*)d_in[3];
    const float* b_attn      = (const float*)d_in[4];
    const float* w_attn_proj = (const float*)d_in[5];
    const float* b_attn_proj = (const float*)d_in[6];
    const float* ln2_g       = (const float*)d_in[7];
    const float* ln2_b       = (const float*)d_in[8];
    const float* w_fc        = (const float*)d_in[9];
    const float* b_fc        = (const float*)d_in[10];
    const float* w_mlp_proj  = (const float*)d_in[11];
    const float* b_mlp_proj  = (const float*)d_in[12];

    char* ws = (char*)d_ws;
    size_t off = 0;
    auto alloc = [&](size_t n) -> void* {
        off = (off + 255) & ~(size_t)255;
        void* p = ws + off;
        off += n;
        return p;
    };
    bf16* wqkvT  = (bf16*)alloc((size_t)C3 * N_EMBD * 2);
    bf16* wprojT = (bf16*)alloc((size_t)N_EMBD * N_EMBD * 2);
    bf16* wfcT   = (bf16*)alloc((size_t)4 * N_EMBD * N_EMBD * 2);
    bf16* wmlpT  = (bf16*)alloc((size_t)N_EMBD * 4 * N_EMBD * 2);
    bf16* hbuf   = (bf16*)alloc((size_t)ROWS * N_EMBD * 2);
    float* x2    = (float*)alloc((size_t)ROWS * N_EMBD * 4);
    bf16* yb     = (bf16*)alloc((size_t)ROWS * N_EMBD * 2);
    bf16* vtb    = (bf16*)alloc((size_t)BATCH * N_HEAD * 64 * SEQ * 2);
    bf16* big    = (bf16*)alloc((size_t)ROWS * 4 * N_EMBD * 2);
    bf16* qkvb   = big;        // [ROWS, 2304]
    bf16* actb   = big;        // [ROWS, 3072]

    k_transpose_all<<<6912, 256, 0, stream>>>(w_attn, wqkvT, w_attn_proj, wprojT,
                                              w_fc, wfcT, w_mlp_proj, wmlpT);

    k_layernorm<<<ROWS / 4, 256, 0, stream>>>(x, ln1_g, ln1_b, hbuf);
    k_gemm<128, 0, false, true ><<<dim3(C3 / 128,  ROWS / 128), 256, 0, stream>>>(
        hbuf, wqkvT,  b_attn,      nullptr, qkvb, ROWS, C3,     N_EMBD);
    k_vtrans<<<dim3(SEQ / 32, BATCH * N_HEAD, 2), 256, 0, stream>>>(qkvb, vtb);
    k_flash<<<768, 256, 0, stream>>>(qkvb, vtb, yb);
    k_gemm<64,  0, true,  false><<<dim3(N_EMBD / 64, ROWS / 128), 256, 0, stream>>>(
        yb,   wprojT, b_attn_proj, x,       x2,   ROWS, N_EMBD, N_EMBD);
    k_layernorm<<<ROWS / 4, 256, 0, stream>>>(x2, ln2_g, ln2_b, hbuf);
    k_gemm<128, 1, false, true ><<<dim3(3072 / 128, ROWS / 128), 256, 0, stream>>>(
        hbuf, wfcT,   b_fc,        nullptr, actb, ROWS, 3072,   N_EMBD);
    k_gemm<64,  0, true,  false><<<dim3(N_EMBD / 64, ROWS / 128), 256, 0, stream>>>(
        actb, wmlpT,  b_mlp_proj,  x2, (float*)d_out, ROWS, N_EMBD, 3072);
}

// Round 10
// 282.013 us; speedup vs baseline: 1.0933x; 1.0933x over previous
//
#include <hip/hip_runtime.h>
#include <hip/hip_bf16.h>
#include <math.h>

#define N_EMBD 768
#define N_HEAD 12
#define BATCH  2
#define SEQ    2048
#define ROWS   (BATCH*SEQ)   // 4096
#define C3     (3*N_EMBD)    // 2304

typedef __bf16 bf16;
typedef __attribute__((ext_vector_type(8))) __bf16 bf16x8;
typedef __attribute__((ext_vector_type(4))) float f32x4;

// async global->LDS, 16B per lane. LDS dest must be wave-uniform base + 16*lane.
__device__ __forceinline__ void async16(const bf16* g, bf16* l) {
    __builtin_amdgcn_global_load_lds(
        (const __attribute__((address_space(1))) uint32_t*)g,
        (__attribute__((address_space(3))) uint32_t*)l, 16, 0, 0);
}

// ---------------- merged transpose+cast for all 4 weights: in[K,N] -> out[N,K] ----------------
__global__ __launch_bounds__(256) void k_transpose_all(
    const float* __restrict__ w0, bf16* __restrict__ o0,   // attn K=768  N=2304 (1728 tiles)
    const float* __restrict__ w1, bf16* __restrict__ o1,   // proj K=768  N=768  (576)
    const float* __restrict__ w2, bf16* __restrict__ o2,   // fc   K=768  N=3072 (2304)
    const float* __restrict__ w3, bf16* __restrict__ o3)   // mlp  K=3072 N=768  (2304)
{
    __shared__ bf16 tile[32][33];
    int bid = blockIdx.x;
    const float* in; bf16* out; int K, N, local;
    if      (bid < 1728) { in = w0; out = o0; K = 768;  N = 2304; local = bid; }
    else if (bid < 2304) { in = w1; out = o1; K = 768;  N = 768;  local = bid - 1728; }
    else if (bid < 4608) { in = w2; out = o2; K = 768;  N = 3072; local = bid - 2304; }
    else                 { in = w3; out = o3; K = 3072; N = 768;  local = bid - 4608; }
    int nt = N / 32;
    int n0 = (local % nt) * 32, k0 = (local / nt) * 32;
    int tc = threadIdx.x & 31, tr = threadIdx.x >> 5;
    #pragma unroll
    for (int i = 0; i < 4; i++) {
        int r = tr + i * 8;
        tile[r][tc] = (bf16)in[(size_t)(k0 + r) * N + n0 + tc];
    }
    __syncthreads();
    #pragma unroll
    for (int i = 0; i < 4; i++) {
        int r = tr + i * 8;
        out[(size_t)(n0 + r) * K + k0 + tc] = tile[tc][r];
    }
}

// ---------------- V transpose: qkv[t][2C + h*64 + d] -> vt[(bh*64+d)*SEQ + t] ----------------
__global__ __launch_bounds__(256) void k_vtrans(
    const bf16* __restrict__ qkv, bf16* __restrict__ vt)
{
    __shared__ bf16 tile[32][33];
    int tt = blockIdx.x;                 // t tile (SEQ/32)
    int bh = blockIdx.y;                 // 24
    int dt = blockIdx.z;                 // d tile (2)
    int b = bh / N_HEAD, h = bh % N_HEAD;
    int tc = threadIdx.x & 31, tr = threadIdx.x >> 5;
    #pragma unroll
    for (int i = 0; i < 4; i++) {
        int r = tr + i * 8;              // t offset
        tile[r][tc] = qkv[(size_t)(b * SEQ + tt * 32 + r) * C3 + 2 * N_EMBD + h * 64 + dt * 32 + tc];
    }
    __syncthreads();
    #pragma unroll
    for (int i = 0; i < 4; i++) {
        int r = tr + i * 8;              // d offset
        vt[(size_t)(bh * 64 + dt * 32 + r) * SEQ + tt * 32 + tc] = tile[tc][r];
    }
}

// ---------------- LayerNorm fp32 -> bf16, one wave per row, float4 loads ----------------
__global__ __launch_bounds__(256) void k_layernorm(
    const float* __restrict__ x, const float* __restrict__ g,
    const float* __restrict__ b, bf16* __restrict__ out)
{
    int wave = threadIdx.x >> 6, lane = threadIdx.x & 63;
    int row = blockIdx.x * 4 + wave;
    const float4* xr = (const float4*)(x + (size_t)row * N_EMBD);
    const float4* g4 = (const float4*)g;
    const float4* b4 = (const float4*)b;
    float4 v[3];
    float s = 0.f, sq = 0.f;
    #pragma unroll
    for (int i = 0; i < 3; i++) {
        v[i] = xr[lane + 64 * i];
        s  += v[i].x + v[i].y + v[i].z + v[i].w;
        sq += v[i].x * v[i].x + v[i].y * v[i].y + v[i].z * v[i].z + v[i].w * v[i].w;
    }
    #pragma unroll
    for (int off = 32; off > 0; off >>= 1) {
        s  += __shfl_xor(s, off);
        sq += __shfl_xor(sq, off);
    }
    float mu  = s * (1.f / N_EMBD);
    float var = sq * (1.f / N_EMBD) - mu * mu;
    float rs  = rsqrtf(var + 1e-5f);
    bf16* orow = out + (size_t)row * N_EMBD;
    #pragma unroll
    for (int i = 0; i < 3; i++) {
        float4 gv = g4[lane + 64 * i], bv = b4[lane + 64 * i];
        union { ushort4 u4; bf16 e[4]; } pk;
        pk.e[0] = (bf16)((v[i].x - mu) * rs * gv.x + bv.x);
        pk.e[1] = (bf16)((v[i].y - mu) * rs * gv.y + bv.y);
        pk.e[2] = (bf16)((v[i].z - mu) * rs * gv.z + bv.z);
        pk.e[3] = (bf16)((v[i].w - mu) * rs * gv.w + bv.w);
        *(ushort4*)&orow[(lane + 64 * i) * 4] = pk.u4;
    }
}

// ---------------- GEMM: out = act(A[M,K] @ Bt[N,K]^T + bias) (+res) ----------------
// r6-validated core: 128xBN tile, BK=64, async16 staging, kh-XOR swizzle (0 conflicts).
// MSWAP: blockIdx.x = m-tile (A-tile sharers land on one XCD since gridDim.x=32).
// DBUF: double-buffered LDS, one barrier/iter; drain overlaps a full compute. Only for
// BN=64 (48 KB LDS keeps 3 blocks/CU).
template<int BN, int ACT, bool RES, bool OUT_BF16, bool MSWAP, bool DBUF>
__global__ __launch_bounds__(256) void k_gemm(
    const bf16* __restrict__ A, const bf16* __restrict__ Bt,
    const float* __restrict__ bias, const float* __restrict__ res,
    void* __restrict__ outp, int M, int N, int K)
{
    constexpr int WC  = BN / 64;
    constexpr int WR  = 4 / WC;
    constexpr int RPW = 128 / WR;
    constexpr int MI  = RPW / 16;
    constexpr int NB  = DBUF ? 2 : 1;
    __shared__ __align__(16) bf16 As[NB][128 * 64];
    __shared__ __align__(16) bf16 Bs[NB][BN * 64];
    int n0 = (MSWAP ? blockIdx.y : blockIdx.x) * BN;
    int m0 = (MSWAP ? blockIdx.x : blockIdx.y) * 128;
    int t = threadIdx.x;
    int lane = t & 63, wave = t >> 6;
    int wr = wave / WC, wc = wave % WC;
    int quad = lane >> 4, l16 = lane & 15;

    f32x4 acc[MI][4];
    #pragma unroll
    for (int i = 0; i < MI; i++)
        #pragma unroll
        for (int j = 0; j < 4; j++) acc[i][j] = (f32x4){0.f, 0.f, 0.f, 0.f};

    int sr = t >> 3;            // 0..31 (row)
    int sc = t & 7;             // chunk 0..7 (8 bf16 = 16B)
    int gsw = (sc ^ (sr & 7)) * 8;   // swizzled global column offset

    auto stage = [&](int k0, int bi) {
        #pragma unroll
        for (int p = 0; p < 4; p++) {
            int r = sr + p * 32;
            async16(&A[(size_t)(m0 + r) * K + k0 + gsw], &As[bi][r * 64 + sc * 8]);
        }
        #pragma unroll
        for (int p = 0; p < BN / 32; p++) {
            int r = sr + p * 32;
            async16(&Bt[(size_t)(n0 + r) * K + k0 + gsw], &Bs[bi][r * 64 + sc * 8]);
        }
    };
    auto compute = [&](int bi) {
        #pragma unroll
        for (int kh = 0; kh < 2; kh++) {
            bf16x8 af[MI], bfv[4];
            #pragma unroll
            for (int i = 0; i < MI; i++)
                af[i]  = *(bf16x8*)&As[bi][(wr * RPW + i * 16 + l16) * 64 + (((quad + 4 * kh) ^ (l16 & 7)) * 8)];
            #pragma unroll
            for (int j = 0; j < 4; j++)
                bfv[j] = *(bf16x8*)&Bs[bi][(wc * 64 + j * 16 + l16) * 64 + (((quad + 4 * kh) ^ (l16 & 7)) * 8)];
            #pragma unroll
            for (int i = 0; i < MI; i++)
                #pragma unroll
                for (int j = 0; j < 4; j++)
                    acc[i][j] = __builtin_amdgcn_mfma_f32_16x16x32_bf16(af[i], bfv[j], acc[i][j], 0, 0, 0);
        }
    };

    if (DBUF) {
        stage(0, 0);
        int bi = 0;
        for (int k0 = 0; k0 < K; k0 += 64, bi ^= 1) {
            __syncthreads();                  // drains stage(k0) (issued a compute ago);
                                              // buf bi^1 readers finished last iter (WAR ok)
            if (k0 + 64 < K) stage(k0 + 64, bi ^ 1);
            compute(bi);
        }
    } else {
        for (int k0 = 0; k0 < K; k0 += 64) {
            __syncthreads();
            stage(k0, 0);
            __syncthreads();
            compute(0);
        }
    }

    float* outf = (float*)outp;
    bf16*  outb = (bf16*)outp;
    #pragma unroll
    for (int i = 0; i < MI; i++) {
        #pragma unroll
        for (int j = 0; j < 4; j++) {
            int col = n0 + wc * 64 + j * 16 + l16;
            float bv = bias[col];
            #pragma unroll
            for (int r = 0; r < 4; r++) {
                int row = m0 + wr * RPW + i * 16 + quad * 4 + r;
                float v = acc[i][j][r] + bv;
                if (ACT == 1) {
                    float z = 0.7978845608f * (v + 0.044715f * v * v * v);
                    v = v / (1.f + __expf(-2.f * z));   // 0.5v(1+tanh z) == v*sigmoid(2z)
                }
                if (RES) v += res[(size_t)row * N + col];
                if (OUT_BF16) outb[(size_t)row * N + col] = (bf16)v;
                else          outf[(size_t)row * N + col] = v;
            }
        }
    }
}

// ---------------- Flash attention v6 (r6-best): balanced constant-sum triples + dbuf ----------------
#define PS_S 72
__global__ __launch_bounds__(256) void k_flash(
    const bf16* __restrict__ qkv, const bf16* __restrict__ vt, bf16* __restrict__ y)
{
    __shared__ __align__(16) bf16 Ks[2][64 * 64];      // [buf][key][d^swz]
    __shared__ __align__(16) bf16 VTl[2][64 * 64];     // [buf][d][key^swz]
    __shared__ __align__(16) bf16 Ps[4][16 * PS_S];    // per-wave [q][key]
    int bid = blockIdx.x;
    int hi = bid >> 8;                   // 0..2
    int lo = bid & 255;
    int g  = lo >> 3;                    // 0..31
    int e  = lo & 7;                     // 0..7
    int bh = hi * 8 + e;                 // 0..23
    int qt;
    if      (hi == 0) qt = g;
    else if (hi == 1) qt = (g + 16) & 31;
    else              qt = (g < 16) ? (30 - 2 * g) : (63 - 2 * g);
    int b = bh / N_HEAD, h = bh % N_HEAD;
    int t = threadIdx.x, lane = t & 63, wave = t >> 6;
    int quad = lane >> 4, l16 = lane & 15;
    int qbase = qt * 64 + wave * 16;

    // Q fragments, pre-scaled by 1/8
    bf16x8 qa[2];
    {
        const bf16* qrow = qkv + (size_t)(b * SEQ + qbase + l16) * C3 + h * 64;
        #pragma unroll
        for (int kh = 0; kh < 2; kh++) {
            union { uint4 u4; bf16 e8[8]; bf16x8 vv; } uq;
            uq.u4 = *(const uint4*)&qrow[quad * 8 + kh * 32];
            #pragma unroll
            for (int j = 0; j < 8; j++) uq.e8[j] = (bf16)((float)uq.e8[j] * 0.125f);
            qa[kh] = uq.vv;
        }
    }
    float l_part[4] = {0.f, 0.f, 0.f, 0.f};
    f32x4 o[4];
    #pragma unroll
    for (int j = 0; j < 4; j++) o[j] = (f32x4){0.f, 0.f, 0.f, 0.f};

    int sr = t >> 3;                 // 0..31
    int sc = t & 7;                  // 16B chunk
    int gsw = (sc ^ (sr & 7)) * 8;   // swizzled column offset

    const bf16* kg = qkv + (size_t)b * SEQ * C3 + N_EMBD + h * 64;
    const bf16* vg = vt + (size_t)bh * 64 * SEQ;

    auto stage = [&](int tile, int bufi) {
        int k0 = tile * 64;
        #pragma unroll
        for (int p = 0; p < 2; p++) {
            int rr = sr + 32 * p;
            async16(&kg[(size_t)(k0 + rr) * C3 + gsw],  &Ks[bufi][rr * 64 + sc * 8]);
            async16(&vg[(size_t)rr * SEQ + k0 + gsw], &VTl[bufi][rr * 64 + sc * 8]);
        }
    };

    int ntiles = qt + 1;
    stage(0, 0);

    for (int tt = 0; tt < ntiles; tt++) {
        int bufi = tt & 1;
        int k0 = tt * 64;
        __syncthreads();                       // drains buf's loads (issued a full tile ago)
        if (tt + 1 < ntiles) stage(tt + 1, bufi ^ 1);

        // S = Q K^T : 4 key-tiles of 16
        f32x4 s[4];
        #pragma unroll
        for (int nt = 0; nt < 4; nt++) {
            bf16x8 b0 = *(bf16x8*)&Ks[bufi][(nt * 16 + l16) * 64 + (((quad    ) ^ (l16 & 7)) * 8)];
            bf16x8 b1 = *(bf16x8*)&Ks[bufi][(nt * 16 + l16) * 64 + (((quad + 4) ^ (l16 & 7)) * 8)];
            f32x4 z = (f32x4){0.f, 0.f, 0.f, 0.f};
            z = __builtin_amdgcn_mfma_f32_16x16x32_bf16(qa[0], b0, z, 0, 0, 0);
            z = __builtin_amdgcn_mfma_f32_16x16x32_bf16(qa[1], b1, z, 0, 0, 0);
            s[nt] = z;
        }
        // p = exp(s); causal zeroing only on the diagonal tile
        bool diag = (tt == qt);
        float p[4][4];
        #pragma unroll
        for (int nt = 0; nt < 4; nt++) {
            int key = k0 + nt * 16 + l16;
            #pragma unroll
            for (int r = 0; r < 4; r++) {
                float pv = __expf(s[nt][r]);
                if (diag && key > qbase + quad * 4 + r) pv = 0.f;
                p[nt][r] = pv;
                l_part[r] += pv;
            }
        }
        // P: C-layout -> per-wave LDS -> A-layout (wave-local, no block barrier)
        #pragma unroll
        for (int nt = 0; nt < 4; nt++)
            #pragma unroll
            for (int r = 0; r < 4; r++)
                Ps[wave][(quad * 4 + r) * PS_S + nt * 16 + l16] = (bf16)p[nt][r];
        bf16x8 pa[2];
        #pragma unroll
        for (int kt = 0; kt < 2; kt++)
            pa[kt] = *(bf16x8*)&Ps[wave][l16 * PS_S + kt * 32 + quad * 8];
        // O += P V
        #pragma unroll
        for (int jt = 0; jt < 4; jt++) {
            int d = jt * 16 + l16;
            #pragma unroll
            for (int kt = 0; kt < 2; kt++) {
                bf16x8 vb = *(bf16x8*)&VTl[bufi][d * 64 + (((quad + 4 * kt) ^ (l16 & 7)) * 8)];
                o[jt] = __builtin_amdgcn_mfma_f32_16x16x32_bf16(pa[kt], vb, o[jt], 0, 0, 0);
            }
        }
    }
    // epilogue: reduce row sums across the 16-lane key groups, divide, store
    #pragma unroll
    for (int r = 0; r < 4; r++) {
        #pragma unroll
        for (int off = 8; off > 0; off >>= 1) l_part[r] += __shfl_xor(l_part[r], off);
    }
    #pragma unroll
    for (int jt = 0; jt < 4; jt++)
        #pragma unroll
        for (int r = 0; r < 4; r++) {
            int q = qbase + quad * 4 + r;
            y[(size_t)(b * SEQ + q) * N_EMBD + h * 64 + jt * 16 + l16] =
                (bf16)(o[jt][r] / l_part[r]);
        }
}

// ---------------- launcher ----------------
extern "C" void kernel_launch(void* const* d_in, const int* in_sizes, int n_in,
                              void* d_out, int out_size, void* d_ws, size_t ws_size,
                              hipStream_t stream) {
    const float* x           = (const float*)d_in[0];
    const float* ln1_g       = (const float*)d_in[1];
    const float* ln1_b       = (const float*)d_in[2];
    const float* w_attn      = (const float*)d_in[3];
    const float* b_attn      = (const float*)d_in[4];
    const float* w_attn_proj = (const float*)d_in[5];
    const float* b_attn_proj = (const float*)d_in[6];
    const float* ln2_g       = (const float*)d_in[7];
    const float* ln2_b       = (const float*)d_in[8];
    const float* w_fc        = (const float*)d_in[9];
    const float* b_fc        = (const float*)d_in[10];
    const float* w_mlp_proj  = (const float*)d_in[11];
    const float* b_mlp_proj  = (const float*)d_in[12];

    char* ws = (char*)d_ws;
    size_t off = 0;
    auto alloc = [&](size_t n) -> void* {
        off = (off + 255) & ~(size_t)255;
        void* p = ws + off;
        off += n;
        return p;
    };
    bf16* wqkvT  = (bf16*)alloc((size_t)C3 * N_EMBD * 2);
    bf16* wprojT = (bf16*)alloc((size_t)N_EMBD * N_EMBD * 2);
    bf16* wfcT   = (bf16*)alloc((size_t)4 * N_EMBD * N_EMBD * 2);
    bf16* wmlpT  = (bf16*)alloc((size_t)N_EMBD * 4 * N_EMBD * 2);
    bf16* hbuf   = (bf16*)alloc((size_t)ROWS * N_EMBD * 2);
    float* x2    = (float*)alloc((size_t)ROWS * N_EMBD * 4);
    bf16* yb     = (bf16*)alloc((size_t)ROWS * N_EMBD * 2);
    bf16* vtb    = (bf16*)alloc((size_t)BATCH * N_HEAD * 64 * SEQ * 2);
    bf16* big    = (bf16*)alloc((size_t)ROWS * 4 * N_EMBD * 2);
    bf16* qkvb   = big;        // [ROWS, 2304]
    bf16* actb   = big;        // [ROWS, 3072]

    k_transpose_all<<<6912, 256, 0, stream>>>(w_attn, wqkvT, w_attn_proj, wprojT,
                                              w_fc, wfcT, w_mlp_proj, wmlpT);

    k_layernorm<<<ROWS / 4, 256, 0, stream>>>(x, ln1_g, ln1_b, hbuf);
    // qkv: untransposed grid (control)
    k_gemm<128, 0, false, true,  false, false><<<dim3(C3 / 128, ROWS / 128), 256, 0, stream>>>(
        hbuf, wqkvT,  b_attn,      nullptr, qkvb, ROWS, C3,     N_EMBD);
    k_vtrans<<<dim3(SEQ / 32, BATCH * N_HEAD, 2), 256, 0, stream>>>(qkvb, vtb);
    k_flash<<<768, 256, 0, stream>>>(qkvb, vtb, yb);
    // proj: m-fast grid + dbuf
    k_gemm<64,  0, true,  false, true,  true ><<<dim3(ROWS / 128, N_EMBD / 64), 256, 0, stream>>>(
        yb,   wprojT, b_attn_proj, x,       x2,   ROWS, N_EMBD, N_EMBD);
    k_layernorm<<<ROWS / 4, 256, 0, stream>>>(x2, ln2_g, ln2_b, hbuf);
    // fc: m-fast grid, single-buffer (BN=128)
    k_gemm<128, 1, false, true,  true,  false><<<dim3(ROWS / 128, 3072 / 128), 256, 0, stream>>>(
        hbuf, wfcT,   b_fc,        nullptr, actb, ROWS, 3072,   N_EMBD);
    // mlp: m-fast grid + dbuf
    k_gemm<64,  0, true,  false, true,  true ><<<dim3(ROWS / 128, N_EMBD / 64), 256, 0, stream>>>(
        actb, wmlpT,  b_mlp_proj,  x2, (float*)d_out, ROWS, N_EMBD, 3072);
}

// Round 11
// 276.749 us; speedup vs baseline: 1.1141x; 1.0190x over previous
//
#include <hip/hip_runtime.h>
#include <hip/hip_bf16.h>
#include <math.h>

#define N_EMBD 768
#define N_HEAD 12
#define BATCH  2
#define SEQ    2048
#define ROWS   (BATCH*SEQ)   // 4096
#define C3     (3*N_EMBD)    // 2304

typedef __bf16 bf16;
typedef __attribute__((ext_vector_type(8))) __bf16 bf16x8;
typedef __attribute__((ext_vector_type(4))) float f32x4;

// async global->LDS, 16B per lane. LDS dest must be wave-uniform base + 16*lane.
__device__ __forceinline__ void async16(const bf16* g, bf16* l) {
    __builtin_amdgcn_global_load_lds(
        (const __attribute__((address_space(1))) uint32_t*)g,
        (__attribute__((address_space(3))) uint32_t*)l, 16, 0, 0);
}

// ---------------- merged transpose+cast for all 4 weights: in[K,N] -> out[N,K] ----------------
__global__ __launch_bounds__(256) void k_transpose_all(
    const float* __restrict__ w0, bf16* __restrict__ o0,   // attn K=768  N=2304 (1728 tiles)
    const float* __restrict__ w1, bf16* __restrict__ o1,   // proj K=768  N=768  (576)
    const float* __restrict__ w2, bf16* __restrict__ o2,   // fc   K=768  N=3072 (2304)
    const float* __restrict__ w3, bf16* __restrict__ o3)   // mlp  K=3072 N=768  (2304)
{
    __shared__ bf16 tile[32][33];
    int bid = blockIdx.x;
    const float* in; bf16* out; int K, N, local;
    if      (bid < 1728) { in = w0; out = o0; K = 768;  N = 2304; local = bid; }
    else if (bid < 2304) { in = w1; out = o1; K = 768;  N = 768;  local = bid - 1728; }
    else if (bid < 4608) { in = w2; out = o2; K = 768;  N = 3072; local = bid - 2304; }
    else                 { in = w3; out = o3; K = 3072; N = 768;  local = bid - 4608; }
    int nt = N / 32;
    int n0 = (local % nt) * 32, k0 = (local / nt) * 32;
    int tc = threadIdx.x & 31, tr = threadIdx.x >> 5;
    #pragma unroll
    for (int i = 0; i < 4; i++) {
        int r = tr + i * 8;
        tile[r][tc] = (bf16)in[(size_t)(k0 + r) * N + n0 + tc];
    }
    __syncthreads();
    #pragma unroll
    for (int i = 0; i < 4; i++) {
        int r = tr + i * 8;
        out[(size_t)(n0 + r) * K + k0 + tc] = tile[tc][r];
    }
}

// ---------------- V transpose: qkv[t][2C + h*64 + d] -> vt[(bh*64+d)*SEQ + t] ----------------
__global__ __launch_bounds__(256) void k_vtrans(
    const bf16* __restrict__ qkv, bf16* __restrict__ vt)
{
    __shared__ bf16 tile[32][33];
    int tt = blockIdx.x;                 // t tile (SEQ/32)
    int bh = blockIdx.y;                 // 24
    int dt = blockIdx.z;                 // d tile (2)
    int b = bh / N_HEAD, h = bh % N_HEAD;
    int tc = threadIdx.x & 31, tr = threadIdx.x >> 5;
    #pragma unroll
    for (int i = 0; i < 4; i++) {
        int r = tr + i * 8;              // t offset
        tile[r][tc] = qkv[(size_t)(b * SEQ + tt * 32 + r) * C3 + 2 * N_EMBD + h * 64 + dt * 32 + tc];
    }
    __syncthreads();
    #pragma unroll
    for (int i = 0; i < 4; i++) {
        int r = tr + i * 8;              // d offset
        vt[(size_t)(bh * 64 + dt * 32 + r) * SEQ + tt * 32 + tc] = tile[tc][r];
    }
}

// ---------------- LayerNorm fp32 -> bf16, one wave per row, float4 loads ----------------
__global__ __launch_bounds__(256) void k_layernorm(
    const float* __restrict__ x, const float* __restrict__ g,
    const float* __restrict__ b, bf16* __restrict__ out)
{
    int wave = threadIdx.x >> 6, lane = threadIdx.x & 63;
    int row = blockIdx.x * 4 + wave;
    const float4* xr = (const float4*)(x + (size_t)row * N_EMBD);
    const float4* g4 = (const float4*)g;
    const float4* b4 = (const float4*)b;
    float4 v[3];
    float s = 0.f, sq = 0.f;
    #pragma unroll
    for (int i = 0; i < 3; i++) {
        v[i] = xr[lane + 64 * i];
        s  += v[i].x + v[i].y + v[i].z + v[i].w;
        sq += v[i].x * v[i].x + v[i].y * v[i].y + v[i].z * v[i].z + v[i].w * v[i].w;
    }
    #pragma unroll
    for (int off = 32; off > 0; off >>= 1) {
        s  += __shfl_xor(s, off);
        sq += __shfl_xor(sq, off);
    }
    float mu  = s * (1.f / N_EMBD);
    float var = sq * (1.f / N_EMBD) - mu * mu;
    float rs  = rsqrtf(var + 1e-5f);
    bf16* orow = out + (size_t)row * N_EMBD;
    #pragma unroll
    for (int i = 0; i < 3; i++) {
        float4 gv = g4[lane + 64 * i], bv = b4[lane + 64 * i];
        union { ushort4 u4; bf16 e[4]; } pk;
        pk.e[0] = (bf16)((v[i].x - mu) * rs * gv.x + bv.x);
        pk.e[1] = (bf16)((v[i].y - mu) * rs * gv.y + bv.y);
        pk.e[2] = (bf16)((v[i].z - mu) * rs * gv.z + bv.z);
        pk.e[3] = (bf16)((v[i].w - mu) * rs * gv.w + bv.w);
        *(ushort4*)&orow[(lane + 64 * i) * 4] = pk.u4;
    }
}

// ---------------- GEMM (4-wave, 128xBN): r6-validated core ----------------
template<int BN, int ACT, bool RES, bool OUT_BF16, bool MSWAP, bool DBUF>
__global__ __launch_bounds__(256) void k_gemm(
    const bf16* __restrict__ A, const bf16* __restrict__ Bt,
    const float* __restrict__ bias, const float* __restrict__ res,
    void* __restrict__ outp, int M, int N, int K)
{
    constexpr int WC  = BN / 64;
    constexpr int WR  = 4 / WC;
    constexpr int RPW = 128 / WR;
    constexpr int MI  = RPW / 16;
    constexpr int NB  = DBUF ? 2 : 1;
    __shared__ __align__(16) bf16 As[NB][128 * 64];
    __shared__ __align__(16) bf16 Bs[NB][BN * 64];
    int n0 = (MSWAP ? blockIdx.y : blockIdx.x) * BN;
    int m0 = (MSWAP ? blockIdx.x : blockIdx.y) * 128;
    int t = threadIdx.x;
    int lane = t & 63, wave = t >> 6;
    int wr = wave / WC, wc = wave % WC;
    int quad = lane >> 4, l16 = lane & 15;

    f32x4 acc[MI][4];
    #pragma unroll
    for (int i = 0; i < MI; i++)
        #pragma unroll
        for (int j = 0; j < 4; j++) acc[i][j] = (f32x4){0.f, 0.f, 0.f, 0.f};

    int sr = t >> 3;            // 0..31 (row)
    int sc = t & 7;             // chunk 0..7 (8 bf16 = 16B)
    int gsw = (sc ^ (sr & 7)) * 8;   // swizzled global column offset

    auto stage = [&](int k0, int bi) {
        #pragma unroll
        for (int p = 0; p < 4; p++) {
            int r = sr + p * 32;
            async16(&A[(size_t)(m0 + r) * K + k0 + gsw], &As[bi][r * 64 + sc * 8]);
        }
        #pragma unroll
        for (int p = 0; p < BN / 32; p++) {
            int r = sr + p * 32;
            async16(&Bt[(size_t)(n0 + r) * K + k0 + gsw], &Bs[bi][r * 64 + sc * 8]);
        }
    };
    auto compute = [&](int bi) {
        #pragma unroll
        for (int kh = 0; kh < 2; kh++) {
            bf16x8 af[MI], bfv[4];
            #pragma unroll
            for (int i = 0; i < MI; i++)
                af[i]  = *(bf16x8*)&As[bi][(wr * RPW + i * 16 + l16) * 64 + (((quad + 4 * kh) ^ (l16 & 7)) * 8)];
            #pragma unroll
            for (int j = 0; j < 4; j++)
                bfv[j] = *(bf16x8*)&Bs[bi][(wc * 64 + j * 16 + l16) * 64 + (((quad + 4 * kh) ^ (l16 & 7)) * 8)];
            #pragma unroll
            for (int i = 0; i < MI; i++)
                #pragma unroll
                for (int j = 0; j < 4; j++)
                    acc[i][j] = __builtin_amdgcn_mfma_f32_16x16x32_bf16(af[i], bfv[j], acc[i][j], 0, 0, 0);
        }
    };

    if (DBUF) {
        stage(0, 0);
        int bi = 0;
        for (int k0 = 0; k0 < K; k0 += 64, bi ^= 1) {
            __syncthreads();
            if (k0 + 64 < K) stage(k0 + 64, bi ^ 1);
            compute(bi);
        }
    } else {
        for (int k0 = 0; k0 < K; k0 += 64) {
            __syncthreads();
            stage(k0, 0);
            __syncthreads();
            compute(0);
        }
    }

    float* outf = (float*)outp;
    bf16*  outb = (bf16*)outp;
    #pragma unroll
    for (int i = 0; i < MI; i++) {
        #pragma unroll
        for (int j = 0; j < 4; j++) {
            int col = n0 + wc * 64 + j * 16 + l16;
            float bv = bias[col];
            #pragma unroll
            for (int r = 0; r < 4; r++) {
                int row = m0 + wr * RPW + i * 16 + quad * 4 + r;
                float v = acc[i][j][r] + bv;
                if (ACT == 1) {
                    float z = 0.7978845608f * (v + 0.044715f * v * v * v);
                    v = v / (1.f + __expf(-2.f * z));   // 0.5v(1+tanh z) == v*sigmoid(2z)
                }
                if (RES) v += res[(size_t)row * N + col];
                if (OUT_BF16) outb[(size_t)row * N + col] = (bf16)v;
                else          outf[(size_t)row * N + col] = v;
            }
        }
    }
}

// ---------------- GEMM2 (2-wave, 64x64 tile, dbuf): for N=768 GEMMs ----------------
// grid (M/64, N/64) m-fast: 768 blocks = exactly 3/CU (vs 384 = 1.5/CU for 128-tiles).
// A-band sharers (same blockIdx.x, stride 64 in lid) land on one XCD -> A fetched once.
// fp32 out + residual, no activation.
__global__ __launch_bounds__(128) void k_gemm2(
    const bf16* __restrict__ A, const bf16* __restrict__ Bt,
    const float* __restrict__ bias, const float* __restrict__ res,
    float* __restrict__ outp, int M, int N, int K)
{
    __shared__ __align__(16) bf16 As[2][64 * 64];
    __shared__ __align__(16) bf16 Bs[2][64 * 64];
    int m0 = blockIdx.x * 64, n0 = blockIdx.y * 64;
    int t = threadIdx.x;
    int lane = t & 63, w = t >> 6;       // w 0..1
    int quad = lane >> 4, l16 = lane & 15;

    f32x4 acc[2][4];
    #pragma unroll
    for (int i = 0; i < 2; i++)
        #pragma unroll
        for (int j = 0; j < 4; j++) acc[i][j] = (f32x4){0.f, 0.f, 0.f, 0.f};

    int sr = t >> 3;            // 0..15 (row)
    int sc = t & 7;             // chunk 0..7
    int gsw = (sc ^ (sr & 7)) * 8;   // (sr+16p)&7 == sr&7

    auto stage = [&](int k0, int bi) {
        #pragma unroll
        for (int p = 0; p < 4; p++) {
            int r = sr + p * 16;
            async16(&A[(size_t)(m0 + r) * K + k0 + gsw], &As[bi][r * 64 + sc * 8]);
        }
        #pragma unroll
        for (int p = 0; p < 4; p++) {
            int r = sr + p * 16;
            async16(&Bt[(size_t)(n0 + r) * K + k0 + gsw], &Bs[bi][r * 64 + sc * 8]);
        }
    };
    auto compute = [&](int bi) {
        #pragma unroll
        for (int kh = 0; kh < 2; kh++) {
            int rsw = ((quad + 4 * kh) ^ (l16 & 7)) * 8;
            bf16x8 af[2], bfv[4];
            #pragma unroll
            for (int i = 0; i < 2; i++)
                af[i]  = *(bf16x8*)&As[bi][(w * 32 + i * 16 + l16) * 64 + rsw];
            #pragma unroll
            for (int j = 0; j < 4; j++)
                bfv[j] = *(bf16x8*)&Bs[bi][(j * 16 + l16) * 64 + rsw];
            #pragma unroll
            for (int i = 0; i < 2; i++)
                #pragma unroll
                for (int j = 0; j < 4; j++)
                    acc[i][j] = __builtin_amdgcn_mfma_f32_16x16x32_bf16(af[i], bfv[j], acc[i][j], 0, 0, 0);
        }
    };

    stage(0, 0);
    int bi = 0;
    for (int k0 = 0; k0 < K; k0 += 64, bi ^= 1) {
        __syncthreads();
        if (k0 + 64 < K) stage(k0 + 64, bi ^ 1);
        compute(bi);
    }

    #pragma unroll
    for (int i = 0; i < 2; i++) {
        #pragma unroll
        for (int j = 0; j < 4; j++) {
            int col = n0 + j * 16 + l16;
            float bv = bias[col];
            #pragma unroll
            for (int r = 0; r < 4; r++) {
                int row = m0 + w * 32 + i * 16 + quad * 4 + r;
                outp[(size_t)row * N + col] = acc[i][j][r] + bv + res[(size_t)row * N + col];
            }
        }
    }
}

// ---------------- Flash attention v6 (r6-best): balanced constant-sum triples + dbuf ----------------
#define PS_S 72
__global__ __launch_bounds__(256) void k_flash(
    const bf16* __restrict__ qkv, const bf16* __restrict__ vt, bf16* __restrict__ y)
{
    __shared__ __align__(16) bf16 Ks[2][64 * 64];      // [buf][key][d^swz]
    __shared__ __align__(16) bf16 VTl[2][64 * 64];     // [buf][d][key^swz]
    __shared__ __align__(16) bf16 Ps[4][16 * PS_S];    // per-wave [q][key]
    int bid = blockIdx.x;
    int hi = bid >> 8;                   // 0..2
    int lo = bid & 255;
    int g  = lo >> 3;                    // 0..31
    int e  = lo & 7;                     // 0..7
    int bh = hi * 8 + e;                 // 0..23
    int qt;
    if      (hi == 0) qt = g;
    else if (hi == 1) qt = (g + 16) & 31;
    else              qt = (g < 16) ? (30 - 2 * g) : (63 - 2 * g);
    int b = bh / N_HEAD, h = bh % N_HEAD;
    int t = threadIdx.x, lane = t & 63, wave = t >> 6;
    int quad = lane >> 4, l16 = lane & 15;
    int qbase = qt * 64 + wave * 16;

    // Q fragments, pre-scaled by 1/8
    bf16x8 qa[2];
    {
        const bf16* qrow = qkv + (size_t)(b * SEQ + qbase + l16) * C3 + h * 64;
        #pragma unroll
        for (int kh = 0; kh < 2; kh++) {
            union { uint4 u4; bf16 e8[8]; bf16x8 vv; } uq;
            uq.u4 = *(const uint4*)&qrow[quad * 8 + kh * 32];
            #pragma unroll
            for (int j = 0; j < 8; j++) uq.e8[j] = (bf16)((float)uq.e8[j] * 0.125f);
            qa[kh] = uq.vv;
        }
    }
    float l_part[4] = {0.f, 0.f, 0.f, 0.f};
    f32x4 o[4];
    #pragma unroll
    for (int j = 0; j < 4; j++) o[j] = (f32x4){0.f, 0.f, 0.f, 0.f};

    int sr = t >> 3;                 // 0..31
    int sc = t & 7;                  // 16B chunk
    int gsw = (sc ^ (sr & 7)) * 8;   // swizzled column offset

    const bf16* kg = qkv + (size_t)b * SEQ * C3 + N_EMBD + h * 64;
    const bf16* vg = vt + (size_t)bh * 64 * SEQ;

    auto stage = [&](int tile, int bufi) {
        int k0 = tile * 64;
        #pragma unroll
        for (int p = 0; p < 2; p++) {
            int rr = sr + 32 * p;
            async16(&kg[(size_t)(k0 + rr) * C3 + gsw],  &Ks[bufi][rr * 64 + sc * 8]);
            async16(&vg[(size_t)rr * SEQ + k0 + gsw], &VTl[bufi][rr * 64 + sc * 8]);
        }
    };

    int ntiles = qt + 1;
    stage(0, 0);

    for (int tt = 0; tt < ntiles; tt++) {
        int bufi = tt & 1;
        int k0 = tt * 64;
        __syncthreads();                       // drains buf's loads (issued a full tile ago)
        if (tt + 1 < ntiles) stage(tt + 1, bufi ^ 1);

        // S = Q K^T : 4 key-tiles of 16
        f32x4 s[4];
        #pragma unroll
        for (int nt = 0; nt < 4; nt++) {
            bf16x8 b0 = *(bf16x8*)&Ks[bufi][(nt * 16 + l16) * 64 + (((quad    ) ^ (l16 & 7)) * 8)];
            bf16x8 b1 = *(bf16x8*)&Ks[bufi][(nt * 16 + l16) * 64 + (((quad + 4) ^ (l16 & 7)) * 8)];
            f32x4 z = (f32x4){0.f, 0.f, 0.f, 0.f};
            z = __builtin_amdgcn_mfma_f32_16x16x32_bf16(qa[0], b0, z, 0, 0, 0);
            z = __builtin_amdgcn_mfma_f32_16x16x32_bf16(qa[1], b1, z, 0, 0, 0);
            s[nt] = z;
        }
        // p = exp(s); causal zeroing only on the diagonal tile
        bool diag = (tt == qt);
        float p[4][4];
        #pragma unroll
        for (int nt = 0; nt < 4; nt++) {
            int key = k0 + nt * 16 + l16;
            #pragma unroll
            for (int r = 0; r < 4; r++) {
                float pv = __expf(s[nt][r]);
                if (diag && key > qbase + quad * 4 + r) pv = 0.f;
                p[nt][r] = pv;
                l_part[r] += pv;
            }
        }
        // P: C-layout -> per-wave LDS -> A-layout (wave-local, no block barrier)
        #pragma unroll
        for (int nt = 0; nt < 4; nt++)
            #pragma unroll
            for (int r = 0; r < 4; r++)
                Ps[wave][(quad * 4 + r) * PS_S + nt * 16 + l16] = (bf16)p[nt][r];
        bf16x8 pa[2];
        #pragma unroll
        for (int kt = 0; kt < 2; kt++)
            pa[kt] = *(bf16x8*)&Ps[wave][l16 * PS_S + kt * 32 + quad * 8];
        // O += P V
        #pragma unroll
        for (int jt = 0; jt < 4; jt++) {
            int d = jt * 16 + l16;
            #pragma unroll
            for (int kt = 0; kt < 2; kt++) {
                bf16x8 vb = *(bf16x8*)&VTl[bufi][d * 64 + (((quad + 4 * kt) ^ (l16 & 7)) * 8)];
                o[jt] = __builtin_amdgcn_mfma_f32_16x16x32_bf16(pa[kt], vb, o[jt], 0, 0, 0);
            }
        }
    }
    // epilogue: reduce row sums across the 16-lane key groups, divide, store
    #pragma unroll
    for (int r = 0; r < 4; r++) {
        #pragma unroll
        for (int off = 8; off > 0; off >>= 1) l_part[r] += __shfl_xor(l_part[r], off);
    }
    #pragma unroll
    for (int jt = 0; jt < 4; jt++)
        #pragma unroll
        for (int r = 0; r < 4; r++) {
            int q = qbase + quad * 4 + r;
            y[(size_t)(b * SEQ + q) * N_EMBD + h * 64 + jt * 16 + l16] =
                (bf16)(o[jt][r] / l_part[r]);
        }
}

// ---------------- launcher ----------------
extern "C" void kernel_launch(void* const* d_in, const int* in_sizes, int n_in,
                              void* d_out, int out_size, void* d_ws, size_t ws_size,
                              hipStream_t stream) {
    const float* x           = (const float*)d_in[0];
    const float* ln1_g       = (const float*)d_in[1];
    const float* ln1_b       = (const float*)d_in[2];
    const float* w_attn      = (const float*)d_in[3];
    const float* b_attn      = (const float*)d_in[4];
    const float* w_attn_proj = (const float*)d_in[5];
    const float* b_attn_proj = (const float*)d_in[6];
    const float* ln2_g       = (const float*)d_in[7];
    const float* ln2_b       = (const float*)d_in[8];
    const float* w_fc        = (const float*)d_in[9];
    const float* b_fc        = (const float*)d_in[10];
    const float* w_mlp_proj  = (const float*)d_in[11];
    const float* b_mlp_proj  = (const float*)d_in[12];

    char* ws = (char*)d_ws;
    size_t off = 0;
    auto alloc = [&](size_t n) -> void* {
        off = (off + 255) & ~(size_t)255;
        void* p = ws + off;
        off += n;
        return p;
    };
    bf16* wqkvT  = (bf16*)alloc((size_t)C3 * N_EMBD * 2);
    bf16* wprojT = (bf16*)alloc((size_t)N_EMBD * N_EMBD * 2);
    bf16* wfcT   = (bf16*)alloc((size_t)4 * N_EMBD * N_EMBD * 2);
    bf16* wmlpT  = (bf16*)alloc((size_t)N_EMBD * 4 * N_EMBD * 2);
    bf16* hbuf   = (bf16*)alloc((size_t)ROWS * N_EMBD * 2);
    float* x2    = (float*)alloc((size_t)ROWS * N_EMBD * 4);
    bf16* yb     = (bf16*)alloc((size_t)ROWS * N_EMBD * 2);
    bf16* vtb    = (bf16*)alloc((size_t)BATCH * N_HEAD * 64 * SEQ * 2);
    bf16* big    = (bf16*)alloc((size_t)ROWS * 4 * N_EMBD * 2);
    bf16* qkvb   = big;        // [ROWS, 2304]
    bf16* actb   = big;        // [ROWS, 3072]

    k_transpose_all<<<6912, 256, 0, stream>>>(w_attn, wqkvT, w_attn_proj, wprojT,
                                              w_fc, wfcT, w_mlp_proj, wmlpT);

    k_layernorm<<<ROWS / 4, 256, 0, stream>>>(x, ln1_g, ln1_b, hbuf);
    // qkv: m-fast grid for A locality
    k_gemm<128, 0, false, true,  true,  false><<<dim3(ROWS / 128, C3 / 128), 256, 0, stream>>>(
        hbuf, wqkvT,  b_attn,      nullptr, qkvb, ROWS, C3,     N_EMBD);
    k_vtrans<<<dim3(SEQ / 32, BATCH * N_HEAD, 2), 256, 0, stream>>>(qkvb, vtb);
    k_flash<<<768, 256, 0, stream>>>(qkvb, vtb, yb);
    // proj: 64x64 2-wave blocks, 3 blocks/CU
    k_gemm2<<<dim3(ROWS / 64, N_EMBD / 64), 128, 0, stream>>>(
        yb,   wprojT, b_attn_proj, x,       x2,   ROWS, N_EMBD, N_EMBD);
    k_layernorm<<<ROWS / 4, 256, 0, stream>>>(x2, ln2_g, ln2_b, hbuf);
    // fc: m-fast grid, single-buffer (BN=128)
    k_gemm<128, 1, false, true,  true,  false><<<dim3(ROWS / 128, 3072 / 128), 256, 0, stream>>>(
        hbuf, wfcT,   b_fc,        nullptr, actb, ROWS, 3072,   N_EMBD);
    // mlp: 64x64 2-wave blocks, 3 blocks/CU
    k_gemm2<<<dim3(ROWS / 64, N_EMBD / 64), 128, 0, stream>>>(
        actb, wmlpT,  b_mlp_proj,  x2, (float*)d_out, ROWS, N_EMBD, 3072);
}